// Round 14
// baseline (157.642 us; speedup 1.0000x reference)
//
#include <hip/hip_runtime.h>
#include <hip/hip_bf16.h>

#define N_NODES 65536
#define N_EDGES 1048576
#define F_IN    128
#define HEADS   4
#define HID     64
#define NHID    256   // HEADS*HID
#define NBUCK   1024  // coarse buckets = dst>>6
#define BCAP    2048  // slots per bucket

typedef float fx4 __attribute__((ext_vector_type(4)));
typedef short bf16x8 __attribute__((ext_vector_type(8)));
typedef float f32x4 __attribute__((ext_vector_type(4)));
typedef float f32x2 __attribute__((ext_vector_type(2)));

typedef __attribute__((address_space(1))) const unsigned as1_cuint;
typedef __attribute__((address_space(3))) unsigned as3_uint;

__device__ inline unsigned short f2bf(float f) {
    unsigned u = __float_as_uint(f);
    u += 0x7fff + ((u >> 16) & 1);          // round-to-nearest-even
    return (unsigned short)(u >> 16);
}
__device__ inline float bflo(unsigned w) { return __uint_as_float(w << 16); }
__device__ inline float bfhi(unsigned w) { return __uint_as_float(w & 0xffff0000u); }

// DPP-fused add: x + permute(x).
// 0xB1=quad xor1, 0x4E=quad xor2, 0x141=row_half_mirror (i^7 in 8), 0x140=row_mirror (i^15 in 16)
template <int CTRL>
__device__ inline float dpp_add(float x) {
    int y = __builtin_amdgcn_update_dpp(0, __float_as_int(x), CTRL, 0xf, 0xf, true);
    return x + __int_as_float(y);
}

// ---------------------------------------------------------------- K_front: bn_stats (blocks 0..255) || coarse (blocks 256..511)
__global__ __launch_bounds__(256) void k_front(const float* __restrict__ x,
                                               float* __restrict__ sums,
                                               unsigned short* __restrict__ xhi,
                                               const int* __restrict__ ei,
                                               int* __restrict__ ccnt,
                                               unsigned* __restrict__ cbuf) {
    __shared__ int smem[2048];                     // 8KB union
    const int t = threadIdx.x;
    if (blockIdx.x < 256) {
        // ---- BN stats + x -> bf16 (pre-swizzled) ----
        const int lane = t & 63;
        const int w = t >> 6;
        const int wid = blockIdx.x * 4 + w;        // 0..1023 global wave id
        float* sh = (float*)smem;                  // [4][128]
        float s0 = 0.f, s1 = 0.f, q0 = 0.f, q1 = 0.f;
        for (int i = 0; i < 64; ++i) {
            int r = wid + i * 1024;
            float2 v = *(const float2*)(x + (size_t)r * F_IN + lane * 2);
            s0 += v.x; q0 += v.x * v.x;
            s1 += v.y; q1 += v.y * v.y;
            unsigned short h0 = f2bf(v.x), h1 = f2bf(v.y);
            int slot = (lane >> 2) ^ (r & 7);
            int idx = r * 64 + slot * 4 + (lane & 3);
            ((unsigned*)xhi)[idx] = (unsigned)h0 | ((unsigned)h1 << 16);
        }
        sh[w * 128 + lane * 2] = s0; sh[w * 128 + lane * 2 + 1] = s1;
        __syncthreads();
        if (t < 128) atomicAdd(&sums[t], sh[t] + sh[128 + t] + sh[256 + t] + sh[384 + t]);
        __syncthreads();
        sh[w * 128 + lane * 2] = q0; sh[w * 128 + lane * 2 + 1] = q1;
        __syncthreads();
        if (t < 128) atomicAdd(&sums[128 + t], sh[t] + sh[128 + t] + sh[256 + t] + sh[384 + t]);
    } else {
        // ---- coarse bucket partition ----
        int* cnt  = smem;                          // 1024
        int* base = smem + 1024;                   // 1024
        for (int i = t; i < NBUCK; i += 256) cnt[i] = 0;
        __syncthreads();
        const int e0 = (blockIdx.x - 256) * 4096;
        int myrank[16];
        #pragma unroll
        for (int k = 0; k < 16; ++k) {
            int d = ei[N_EDGES + e0 + k * 256 + t];
            myrank[k] = atomicAdd(&cnt[d >> 6], 1);
        }
        __syncthreads();
        for (int i = t; i < NBUCK; i += 256)
            base[i] = (i << 11) + atomicAdd(&ccnt[i], cnt[i]);
        __syncthreads();
        #pragma unroll
        for (int k = 0; k < 16; ++k) {
            int e = e0 + k * 256 + t;
            int s = ei[e];
            int d = ei[N_EDGES + e];
            unsigned pos = (unsigned)(base[d >> 6] + myrank[k]);
            if ((pos >> 11) == (unsigned)(d >> 6))
                cbuf[pos] = (unsigned)s | ((unsigned)(d & 63) << 16);
        }
    }
}

// ---------------------------------------------------------------- prep_w (BN-finalize inlined)
__global__ __launch_bounds__(256) void k_prep_w(const float* __restrict__ w_l,
                                                const float* __restrict__ b_l,
                                                const float* __restrict__ w_r,
                                                const float* __restrict__ b_r,
                                                const float* __restrict__ gamma,
                                                const float* __restrict__ beta,
                                                const float* __restrict__ sums,
                                                unsigned short* __restrict__ Whi,
                                                float* __restrict__ bp) {
    const int t = threadIdx.x;
    const int lane = t & 63;
    const int o = blockIdx.x * 4 + (t >> 6);       // 0..511
    const int k0 = lane * 2, k1 = k0 + 1;
    const float invN = 1.0f / N_NODES;
    float mean0 = sums[k0] * invN, mean1 = sums[k1] * invN;
    float var0 = sums[128 + k0] * invN - mean0 * mean0;
    float var1 = sums[128 + k1] * invN - mean1 * mean1;
    float sc0 = gamma[k0] * rsqrtf(var0 + 1e-5f);
    float sc1 = gamma[k1] * rsqrtf(var1 + 1e-5f);
    float sh0 = beta[k0] - mean0 * sc0;
    float sh1 = beta[k1] - mean1 * sc1;
    const float* wrow = (o < NHID) ? (w_l + (size_t)o * F_IN)
                                   : (w_r + (size_t)(o - NHID) * F_IN);
    float bo = (o < NHID) ? b_l[o] : b_r[o - NHID];
    float2 wv = *(const float2*)(wrow + lane * 2);
    float w0 = wv.x * sc0, w1 = wv.y * sc1;
    int slot = (lane >> 2) ^ (o & 7);
    int idx = o * 64 + slot * 4 + (lane & 3);
    ((unsigned*)Whi)[idx] = (unsigned)f2bf(w0) | ((unsigned)f2bf(w1) << 16);
    float part = sh0 * wv.x + sh1 * wv.y;          // raw W for bias fold
    #pragma unroll
    for (int m = 1; m < 64; m <<= 1) part += __shfl_xor(part, m, 64);
    if (lane == 0) bp[o] = bo + part;
}

// ---------------------------------------------------------------- K_gemm_fine: gemm (blocks 0..2047) || fine (blocks 2048..3071)
__global__ __launch_bounds__(512) void k_gemm_fine(const unsigned short* __restrict__ xhi,
                                                   const unsigned short* __restrict__ Whi,
                                                   const float* __restrict__ bp,
                                                   unsigned short* __restrict__ xs_bf,
                                                   unsigned short* __restrict__ xd_bf,
                                                   const unsigned* __restrict__ cbuf,
                                                   const int* __restrict__ ccnt,
                                                   int* __restrict__ counts,
                                                   int* __restrict__ row_start,
                                                   int* __restrict__ csr) {
    __shared__ __align__(16) char lds[65536];      // gemm: Ahi|Bhi, then C-bounce tile; fine: small union
    const int t = threadIdx.x;
    if (blockIdx.x < 2048) {
        // ---- MFMA GEMM: D = Ahi*Bhi ----
        const int bid = blockIdx.x;
        const int mb = (bid & 7) * 64 + ((bid >> 3) >> 2);   // XCD-partitioned M
        const int nb = (bid >> 3) & 3;
        const int m0 = mb * 128, n0 = nb * 128;
        {
            const unsigned* srcs[2] = {
                (const unsigned*)(xhi + (size_t)m0 * 128),
                (const unsigned*)(Whi + (size_t)n0 * 128)};
            #pragma unroll
            for (int c = 0; c < 2; ++c) {
                #pragma unroll
                for (int q = 0; q < 4; ++q) {
                    int i = (q * 512 + t) * 4;     // uint index; 16B per thread
                    __builtin_amdgcn_global_load_lds(
                        (as1_cuint*)(srcs[c] + i),
                        (as3_uint*)(lds + c * 32768 + i * 4),
                        16, 0, 0);
                }
            }
        }
        __syncthreads();
        const int wvi = t >> 6, lane = t & 63;
        const int wm = wvi >> 2, wn = wvi & 3;
        const int lg = lane >> 4, lr = lane & 15;
        f32x4 acc[4][2] = {};
        #pragma unroll
        for (int ks = 0; ks < 4; ++ks) {
            bf16x8 ah[4], bh[2];
            #pragma unroll
            for (int mi = 0; mi < 4; ++mi) {
                int r = wm * 64 + mi * 16 + lr;
                int off = r * 256 + ((((ks << 2) + lg) ^ (r & 7)) << 4);
                ah[mi] = *(const bf16x8*)(lds + off);
            }
            #pragma unroll
            for (int nj = 0; nj < 2; ++nj) {
                int r = wn * 32 + nj * 16 + lr;
                int off = r * 256 + ((((ks << 2) + lg) ^ (r & 7)) << 4);
                bh[nj] = *(const bf16x8*)(lds + 32768 + off);
            }
            #pragma unroll
            for (int mi = 0; mi < 4; ++mi)
                #pragma unroll
                for (int nj = 0; nj < 2; ++nj)
                    acc[mi][nj] = __builtin_amdgcn_mfma_f32_16x16x32_bf16(ah[mi], bh[nj], acc[mi][nj], 0, 0, 0);
        }
        // ---- epilogue: bounce C through LDS, store coalesced dwordx4 ----
        __syncthreads();                           // all LDS reads done; safe to overwrite
        unsigned short* cs = (unsigned short*)lds; // [128][136] bf16 = 34KB (rows 16B-aligned)
        #pragma unroll
        for (int nj = 0; nj < 2; ++nj) {
            int nc2 = wn * 32 + nj * 16 + lr;      // block-local col
            float bcol = bp[n0 + nc2];
            #pragma unroll
            for (int mi = 0; mi < 4; ++mi) {
                int row = wm * 64 + mi * 16 + lg * 4;
                #pragma unroll
                for (int r = 0; r < 4; ++r)
                    cs[(row + r) * 136 + nc2] = f2bf(acc[mi][nj][r] + bcol);
            }
        }
        __syncthreads();
        {
            unsigned short* outp = (n0 < NHID) ? xs_bf : xd_bf;
            const int ncol0 = n0 & 255;
            int row = t >> 2;                      // 0..127
            int cseg = (t & 3) * 32;               // 32-short (64B) segment
            const unsigned short* src = cs + row * 136 + cseg;
            unsigned short* dst = outp + (size_t)(m0 + row) * NHID + ncol0 + cseg;
            uint4 v0 = *(const uint4*)(src);
            uint4 v1 = *(const uint4*)(src + 8);
            uint4 v2 = *(const uint4*)(src + 16);
            uint4 v3 = *(const uint4*)(src + 24);
            *(uint4*)(dst)      = v0;
            *(uint4*)(dst + 8)  = v1;
            *(uint4*)(dst + 16) = v2;
            *(uint4*)(dst + 24) = v3;
        }
    } else {
        // ---- fine: bucket-prefix + hist + node scan + counts/row_start + scatter (512 thr) ----
        const int b = blockIdx.x - 2048;
        int* nc    = (int*)lds;                    // 64
        int* rowst = nc + 64;                      // 64
        int* red   = rowst + 64;                   // 512
        if (t < 64) nc[t] = 0;
        int s = 0;                                 // bucket base: sum of ccnt[0..b)
        for (int i = t; i < b; i += 512) s += ccnt[i];
        red[t] = s;
        __syncthreads();
        for (int off = 256; off > 0; off >>= 1) {
            if (t < off) red[t] += red[t + off];
            __syncthreads();
        }
        const int cnt = min(ccnt[b], BCAP);
        const unsigned* p = cbuf + (size_t)b * BCAP;
        unsigned w2[4];
        int rank[4];
        #pragma unroll
        for (int k = 0; k < 4; ++k) {
            int e = t + k * 512;
            if (e < cnt) {
                w2[k] = p[e];
                rank[k] = atomicAdd(&nc[(w2[k] >> 16) & 63], 1);
            }
        }
        __syncthreads();
        if (t < 64) {                              // wave 0: scan 64 node counts
            int v = nc[t];
            counts[b * 64 + t] = v;
            int inc = v;
            #pragma unroll
            for (int off = 1; off < 64; off <<= 1) {
                int n = __shfl_up(inc, off, 64);
                if (t >= off) inc += n;
            }
            int rs = red[0] + inc - v;             // exclusive + bucket base
            row_start[b * 64 + t] = rs;
            rowst[t] = rs;
        }
        __syncthreads();
        #pragma unroll
        for (int k = 0; k < 4; ++k) {
            int e = t + k * 512;
            if (e < cnt) {
                int d = (w2[k] >> 16) & 63;
                csr[rowst[d] + rank[k]] = (int)(w2[k] & 0xffffu);
            }
        }
    }
}

// ---------------------------------------------------------------- aggregation
// one wave per dst node; 64 lanes per edge. Lane owns channels [4l,4l+4); head = l>>4.
// Lean math (factorized lrelu dot, fixed-max exp2 softmax), vectorized index fetch,
// 8 gathers in flight (two quad buffers), dual A/B chains.
// At the LLC->L2 random-fill floor: 272MB @ ~3.3 TB/s ~= 83us (R6-R13 invariant).
__global__ __launch_bounds__(256) void k_aggregate(const unsigned short* __restrict__ xs_bf,
                                                   const unsigned short* __restrict__ xd_bf,
                                                   const int* __restrict__ row_start,
                                                   const int* __restrict__ counts,
                                                   const int* __restrict__ csr,
                                                   const float* __restrict__ att,
                                                   const float* __restrict__ bias,
                                                   float* __restrict__ out) {
    const int t = threadIdx.x;
    const int lane = t & 63;
    const int node  = __builtin_amdgcn_readfirstlane(blockIdx.x * 4 + (t >> 6));
    const int start = __builtin_amdgcn_readfirstlane(row_start[node]);
    const int deg   = __builtin_amdgcn_readfirstlane(counts[node]);
    const int total = deg + 1;                     // item 0 = self loop, i>=1 -> csr[i-1]

    // per-lane constants: att*0.6*log2e and xd for 4 channels
    const float CATT = 0.6f * 1.44269504088896f;
    f32x2 att01, att23, xd01, xd23;
    {
        float4 a = *(const float4*)(att + lane * 4);
        att01.x = CATT * a.x; att01.y = CATT * a.y;
        att23.x = CATT * a.z; att23.y = CATT * a.w;
        uint2 xw = *(const uint2*)(xd_bf + (size_t)node * NHID + lane * 4);
        xd01.x = bflo(xw.x); xd01.y = bfhi(xw.x);
        xd23.x = bflo(xw.y); xd23.y = bfhi(xw.y);
    }

    const char* xsb = (const char*)xs_bf;
    const unsigned voff = (unsigned)lane * 8;
    float ssumA = 0.f, ssumB = 0.f;
    f32x2 accA01 = {0.f, 0.f}, accA23 = {0.f, 0.f};
    f32x2 accB01 = {0.f, 0.f}, accB23 = {0.f, 0.f};

#define LDX(S) (*(const uint2*)(xsb + (((size_t)(unsigned)(S)) << 9) + voff))
#define PROC(U, GUARD, KOFF, SS, A01, A23) {                                   \
        f32x2 c01, c23;                                                        \
        c01.x = bflo((U).x); c01.y = bfhi((U).x);                              \
        c23.x = bflo((U).y); c23.y = bfhi((U).y);                              \
        f32x2 sv01 = c01 + xd01, sv23 = c23 + xd23;                            \
        f32x2 dA2 = att01 * c01 + att23 * c23;                                 \
        f32x2 a01v, a23v;                                                      \
        a01v.x = fabsf(sv01.x); a01v.y = fabsf(sv01.y);                        \
        a23v.x = fabsf(sv23.x); a23v.y = fabsf(sv23.y);                        \
        f32x2 dB2 = att01 * a01v + att23 * a23v;                               \
        float d_ = fmaf(0.66666667f, dB2.x + dB2.y, dA2.x + dA2.y);            \
        d_ = dpp_add<0xB1>(d_);                                                \
        d_ = dpp_add<0x4E>(d_);                                                \
        d_ = dpp_add<0x141>(d_);                                               \
        d_ = dpp_add<0x140>(d_);                /* 16-lane head sum */         \
        if (GUARD && j + (KOFF) >= cnt) d_ = -1e30f;                           \
        float p_ = __builtin_amdgcn_exp2f(d_);                                 \
        SS += p_;                                                              \
        f32x2 p2 = {p_, p_};                                                   \
        A01 += p2 * c01; A23 += p2 * c23; }

    for (int base = 0; base < total; base += 64) {
        const int cnt = __builtin_amdgcn_readfirstlane(min(64, total - base));
        // coalesced index load: lane holds item (base+lane); pads/self -> node
        int item = base + lane;
        int idx = node;
        if ((unsigned)(item - 1) < (unsigned)deg)
            idx = csr[start + item - 1];
        // prologue: 8 loads in flight (lanes beyond cnt hold node -> safe addresses)
        uint2 c0 = LDX(__builtin_amdgcn_readlane(idx, 0));
        uint2 c1 = LDX(__builtin_amdgcn_readlane(idx, 1));
        uint2 c2 = LDX(__builtin_amdgcn_readlane(idx, 2));
        uint2 c3 = LDX(__builtin_amdgcn_readlane(idx, 3));
        uint2 c4 = LDX(__builtin_amdgcn_readlane(idx, 4));
        uint2 c5 = LDX(__builtin_amdgcn_readlane(idx, 5));
        uint2 c6 = LDX(__builtin_amdgcn_readlane(idx, 6));
        uint2 c7 = LDX(__builtin_amdgcn_readlane(idx, 7));
        int j = 0;
        for (; j + 4 <= cnt; j += 4) {         // full quads: no pad compares
            uint2 u0 = c0, u1 = c1, u2 = c2, u3 = c3;
            c0 = c4; c1 = c5; c2 = c6; c3 = c7;
            if (j + 8 < cnt) {                 // j <= 52 -> lanes j+8..j+11 <= 63
                c4 = LDX(__builtin_amdgcn_readlane(idx, j + 8));
                c5 = LDX(__builtin_amdgcn_readlane(idx, j + 9));
                c6 = LDX(__builtin_amdgcn_readlane(idx, j + 10));
                c7 = LDX(__builtin_amdgcn_readlane(idx, j + 11));
            }
            PROC(u0, false, 0, ssumA, accA01, accA23)
            PROC(u1, false, 1, ssumB, accB01, accB23)
            PROC(u2, false, 2, ssumA, accA01, accA23)
            PROC(u3, false, 3, ssumB, accB01, accB23)
        }
        if (j < cnt) {                         // tail: 1-3 items, compare-guarded
            uint2 u0 = c0, u1 = c1, u2 = c2, u3 = c3;
            PROC(u0, true, 0, ssumA, accA01, accA23)
            PROC(u1, true, 1, ssumB, accB01, accB23)
            PROC(u2, true, 2, ssumA, accA01, accA23)
            PROC(u3, true, 3, ssumB, accB01, accB23)
        }
    }
#undef PROC
#undef LDX

    // exact merge (fixed-max softmax: plain add)
    float ssum = ssumA + ssumB;
    f32x2 acc01 = accA01 + accB01;
    f32x2 acc23 = accA23 + accB23;

    float inv = __builtin_amdgcn_rcpf(ssum);
    float r0 = acc01.x * inv, r1 = acc01.y * inv;
    float r2 = acc23.x * inv, r3 = acc23.y * inv;
    // head mean: heads of this hid block live at lanes l, l^16, l^32, l^48
    r0 += __shfl_xor(r0, 16, 64); r0 += __shfl_xor(r0, 32, 64);
    r1 += __shfl_xor(r1, 16, 64); r1 += __shfl_xor(r1, 32, 64);
    r2 += __shfl_xor(r2, 16, 64); r2 += __shfl_xor(r2, 32, 64);
    r3 += __shfl_xor(r3, 16, 64); r3 += __shfl_xor(r3, 32, 64);
    if (lane < 16) {
        float4 b4 = *(const float4*)(bias + lane * 4);
        float o0 = r0 * 0.25f + b4.x;
        float o1 = r1 * 0.25f + b4.y;
        float o2 = r2 * 0.25f + b4.z;
        float o3 = r3 * 0.25f + b4.w;
        o0 = (o0 > 0.f) ? o0 : __builtin_amdgcn_exp2f(o0 * 1.44269504f) - 1.0f;
        o1 = (o1 > 0.f) ? o1 : __builtin_amdgcn_exp2f(o1 * 1.44269504f) - 1.0f;
        o2 = (o2 > 0.f) ? o2 : __builtin_amdgcn_exp2f(o2 * 1.44269504f) - 1.0f;
        o3 = (o3 > 0.f) ? o3 : __builtin_amdgcn_exp2f(o3 * 1.44269504f) - 1.0f;
        float4 o = {o0, o1, o2, o3};
        *(float4*)(out + (size_t)node * HID + lane * 4) = o;
    }
}

// ---------------------------------------------------------------- launch
extern "C" void kernel_launch(void* const* d_in, const int* in_sizes, int n_in,
                              void* d_out, int out_size, void* d_ws, size_t ws_size,
                              hipStream_t stream) {
    const float* x     = (const float*)d_in[0];
    const int*   ei    = (const int*)d_in[1];
    const float* gamma = (const float*)d_in[4];
    const float* beta  = (const float*)d_in[5];
    const float* w_l   = (const float*)d_in[6];
    const float* b_l   = (const float*)d_in[7];
    const float* w_r   = (const float*)d_in[8];
    const float* b_r   = (const float*)d_in[9];
    const float* att   = (const float*)d_in[10];
    const float* bias  = (const float*)d_in[11];
    float* out = (float*)d_out;

    char* ws = (char*)d_ws;
    unsigned short* xs_bf = (unsigned short*)ws;                        // 32 MB
    unsigned short* xd_bf = xs_bf + (size_t)N_NODES * NHID;             // 32 MB
    unsigned short* xhi   = xd_bf + (size_t)N_NODES * NHID;             // 16 MB
    unsigned short* Whi   = xhi + (size_t)N_NODES * F_IN;               // 128 KB
    float* bp      = (float*)(Whi + 512 * F_IN);                        // 512
    float* sums    = bp + 512;                                          // 256  (memset from here)
    int* ccnt      = (int*)(sums + 256);                                // 1024 (memset to here)
    int* counts    = ccnt + NBUCK;                                      // 65536
    int* row_start = counts + N_NODES;                                  // 65536
    int* csr       = row_start + N_NODES;                               // 1048576
    unsigned* cbuf = (unsigned*)(csr + N_EDGES);                        // 8 MB

    (void)hipMemsetAsync(sums, 0, (256 + NBUCK) * sizeof(float), stream);

    k_front<<<512, 256, 0, stream>>>(x, sums, xhi, ei, ccnt, cbuf);
    k_prep_w<<<128, 256, 0, stream>>>(w_l, b_l, w_r, b_r, gamma, beta, sums, Whi, bp);
    k_gemm_fine<<<3072, 512, 0, stream>>>(xhi, Whi, bp, xs_bf, xd_bf,
                                          cbuf, ccnt, counts, row_start, csr);
    k_aggregate<<<N_NODES / 4, 256, 0, stream>>>(xs_bf, xd_bf, row_start, counts, csr,
                                                 att, bias, out);
}

// Round 15
// 144.869 us; speedup vs baseline: 1.0882x; 1.0882x over previous
//
#include <hip/hip_runtime.h>
#include <hip/hip_bf16.h>

#define N_NODES 65536
#define N_EDGES 1048576
#define F_IN    128
#define HEADS   4
#define HID     64
#define NHID    256   // HEADS*HID
#define NBUCK   1024  // coarse buckets = dst>>6
#define BCAP    2048  // slots per bucket

typedef float fx4 __attribute__((ext_vector_type(4)));
typedef short bf16x8 __attribute__((ext_vector_type(8)));
typedef float f32x4 __attribute__((ext_vector_type(4)));
typedef float f32x2 __attribute__((ext_vector_type(2)));

typedef __attribute__((address_space(1))) const unsigned as1_cuint;
typedef __attribute__((address_space(3))) unsigned as3_uint;

__device__ inline unsigned short f2bf(float f) {
    unsigned u = __float_as_uint(f);
    u += 0x7fff + ((u >> 16) & 1);          // round-to-nearest-even
    return (unsigned short)(u >> 16);
}
__device__ inline float bflo(unsigned w) { return __uint_as_float(w << 16); }
__device__ inline float bfhi(unsigned w) { return __uint_as_float(w & 0xffff0000u); }

// DPP-fused add: x + permute(x).
// 0xB1=quad xor1, 0x4E=quad xor2, 0x141=row_half_mirror (i^7 in 8), 0x140=row_mirror (i^15 in 16)
template <int CTRL>
__device__ inline float dpp_add(float x) {
    int y = __builtin_amdgcn_update_dpp(0, __float_as_int(x), CTRL, 0xf, 0xf, true);
    return x + __int_as_float(y);
}

// ---------------------------------------------------------------- K_front: bn_stats (blocks 0..255) || coarse (blocks 256..511)
__global__ __launch_bounds__(256) void k_front(const float* __restrict__ x,
                                               float* __restrict__ sums,
                                               unsigned short* __restrict__ xhi,
                                               const int* __restrict__ ei,
                                               int* __restrict__ ccnt,
                                               unsigned* __restrict__ cbuf) {
    __shared__ int smem[2048];                     // 8KB union
    const int t = threadIdx.x;
    if (blockIdx.x < 256) {
        // ---- BN stats + x -> bf16 (pre-swizzled) ----
        const int lane = t & 63;
        const int w = t >> 6;
        const int wid = blockIdx.x * 4 + w;        // 0..1023 global wave id
        float* sh = (float*)smem;                  // [4][128]
        float s0 = 0.f, s1 = 0.f, q0 = 0.f, q1 = 0.f;
        for (int i = 0; i < 64; ++i) {
            int r = wid + i * 1024;
            float2 v = *(const float2*)(x + (size_t)r * F_IN + lane * 2);
            s0 += v.x; q0 += v.x * v.x;
            s1 += v.y; q1 += v.y * v.y;
            unsigned short h0 = f2bf(v.x), h1 = f2bf(v.y);
            int slot = (lane >> 2) ^ (r & 7);
            int idx = r * 64 + slot * 4 + (lane & 3);
            ((unsigned*)xhi)[idx] = (unsigned)h0 | ((unsigned)h1 << 16);
        }
        sh[w * 128 + lane * 2] = s0; sh[w * 128 + lane * 2 + 1] = s1;
        __syncthreads();
        if (t < 128) atomicAdd(&sums[t], sh[t] + sh[128 + t] + sh[256 + t] + sh[384 + t]);
        __syncthreads();
        sh[w * 128 + lane * 2] = q0; sh[w * 128 + lane * 2 + 1] = q1;
        __syncthreads();
        if (t < 128) atomicAdd(&sums[128 + t], sh[t] + sh[128 + t] + sh[256 + t] + sh[384 + t]);
    } else {
        // ---- coarse bucket partition ----
        int* cnt  = smem;                          // 1024
        int* base = smem + 1024;                   // 1024
        for (int i = t; i < NBUCK; i += 256) cnt[i] = 0;
        __syncthreads();
        const int e0 = (blockIdx.x - 256) * 4096;
        int myrank[16];
        #pragma unroll
        for (int k = 0; k < 16; ++k) {
            int d = ei[N_EDGES + e0 + k * 256 + t];
            myrank[k] = atomicAdd(&cnt[d >> 6], 1);
        }
        __syncthreads();
        for (int i = t; i < NBUCK; i += 256)
            base[i] = (i << 11) + atomicAdd(&ccnt[i], cnt[i]);
        __syncthreads();
        #pragma unroll
        for (int k = 0; k < 16; ++k) {
            int e = e0 + k * 256 + t;
            int s = ei[e];
            int d = ei[N_EDGES + e];
            unsigned pos = (unsigned)(base[d >> 6] + myrank[k]);
            if ((pos >> 11) == (unsigned)(d >> 6))
                cbuf[pos] = (unsigned)s | ((unsigned)(d & 63) << 16);
        }
    }
}

// ---------------------------------------------------------------- prep_w (BN-finalize inlined)
__global__ __launch_bounds__(256) void k_prep_w(const float* __restrict__ w_l,
                                                const float* __restrict__ b_l,
                                                const float* __restrict__ w_r,
                                                const float* __restrict__ b_r,
                                                const float* __restrict__ gamma,
                                                const float* __restrict__ beta,
                                                const float* __restrict__ sums,
                                                unsigned short* __restrict__ Whi,
                                                float* __restrict__ bp) {
    const int t = threadIdx.x;
    const int lane = t & 63;
    const int o = blockIdx.x * 4 + (t >> 6);       // 0..511
    const int k0 = lane * 2, k1 = k0 + 1;
    const float invN = 1.0f / N_NODES;
    float mean0 = sums[k0] * invN, mean1 = sums[k1] * invN;
    float var0 = sums[128 + k0] * invN - mean0 * mean0;
    float var1 = sums[128 + k1] * invN - mean1 * mean1;
    float sc0 = gamma[k0] * rsqrtf(var0 + 1e-5f);
    float sc1 = gamma[k1] * rsqrtf(var1 + 1e-5f);
    float sh0 = beta[k0] - mean0 * sc0;
    float sh1 = beta[k1] - mean1 * sc1;
    const float* wrow = (o < NHID) ? (w_l + (size_t)o * F_IN)
                                   : (w_r + (size_t)(o - NHID) * F_IN);
    float bo = (o < NHID) ? b_l[o] : b_r[o - NHID];
    float2 wv = *(const float2*)(wrow + lane * 2);
    float w0 = wv.x * sc0, w1 = wv.y * sc1;
    int slot = (lane >> 2) ^ (o & 7);
    int idx = o * 64 + slot * 4 + (lane & 3);
    ((unsigned*)Whi)[idx] = (unsigned)f2bf(w0) | ((unsigned)f2bf(w1) << 16);
    float part = sh0 * wv.x + sh1 * wv.y;          // raw W for bias fold
    #pragma unroll
    for (int m = 1; m < 64; m <<= 1) part += __shfl_xor(part, m, 64);
    if (lane == 0) bp[o] = bo + part;
}

// ---------------------------------------------------------------- K_gemm_fine: gemm (blocks 0..2047) || fine (blocks 2048..3071)
__global__ __launch_bounds__(512) void k_gemm_fine(const unsigned short* __restrict__ xhi,
                                                   const unsigned short* __restrict__ Whi,
                                                   const float* __restrict__ bp,
                                                   unsigned short* __restrict__ xs_bf,
                                                   unsigned short* __restrict__ xd_bf,
                                                   const unsigned* __restrict__ cbuf,
                                                   const int* __restrict__ ccnt,
                                                   int* __restrict__ counts,
                                                   int* __restrict__ row_start,
                                                   int* __restrict__ csr) {
    __shared__ __align__(16) char lds[65536];      // gemm: Ahi|Bhi; fine: small union
    const int t = threadIdx.x;
    if (blockIdx.x < 2048) {
        // ---- MFMA GEMM: D = Ahi*Bhi ----
        const int bid = blockIdx.x;
        const int mb = (bid & 7) * 64 + ((bid >> 3) >> 2);   // XCD-partitioned M
        const int nb = (bid >> 3) & 3;
        const int m0 = mb * 128, n0 = nb * 128;
        {
            const unsigned* srcs[2] = {
                (const unsigned*)(xhi + (size_t)m0 * 128),
                (const unsigned*)(Whi + (size_t)n0 * 128)};
            #pragma unroll
            for (int c = 0; c < 2; ++c) {
                #pragma unroll
                for (int q = 0; q < 4; ++q) {
                    int i = (q * 512 + t) * 4;     // uint index; 16B per thread
                    __builtin_amdgcn_global_load_lds(
                        (as1_cuint*)(srcs[c] + i),
                        (as3_uint*)(lds + c * 32768 + i * 4),
                        16, 0, 0);
                }
            }
        }
        __syncthreads();
        const int wvi = t >> 6, lane = t & 63;
        const int wm = wvi >> 2, wn = wvi & 3;
        const int lg = lane >> 4, lr = lane & 15;
        f32x4 acc[4][2] = {};
        #pragma unroll
        for (int ks = 0; ks < 4; ++ks) {
            bf16x8 ah[4], bh[2];
            #pragma unroll
            for (int mi = 0; mi < 4; ++mi) {
                int r = wm * 64 + mi * 16 + lr;
                int off = r * 256 + ((((ks << 2) + lg) ^ (r & 7)) << 4);
                ah[mi] = *(const bf16x8*)(lds + off);
            }
            #pragma unroll
            for (int nj = 0; nj < 2; ++nj) {
                int r = wn * 32 + nj * 16 + lr;
                int off = r * 256 + ((((ks << 2) + lg) ^ (r & 7)) << 4);
                bh[nj] = *(const bf16x8*)(lds + 32768 + off);
            }
            #pragma unroll
            for (int mi = 0; mi < 4; ++mi)
                #pragma unroll
                for (int nj = 0; nj < 2; ++nj)
                    acc[mi][nj] = __builtin_amdgcn_mfma_f32_16x16x32_bf16(ah[mi], bh[nj], acc[mi][nj], 0, 0, 0);
        }
        unsigned short* outp = (n0 < NHID) ? xs_bf : xd_bf;
        const int ncol0 = n0 & 255;
        #pragma unroll
        for (int nj = 0; nj < 2; ++nj) {
            int nc2 = wn * 32 + nj * 16 + lr;
            float bcol = bp[n0 + nc2];
            #pragma unroll
            for (int mi = 0; mi < 4; ++mi) {
                #pragma unroll
                for (int r = 0; r < 4; ++r) {
                    int m = m0 + wm * 64 + mi * 16 + lg * 4 + r;
                    outp[(size_t)m * NHID + ncol0 + nc2] = f2bf(acc[mi][nj][r] + bcol);
                }
            }
        }
    } else {
        // ---- fine: bucket-prefix + hist + node scan + counts/row_start + scatter (512 thr) ----
        const int b = blockIdx.x - 2048;
        int* nc    = (int*)lds;                    // 64
        int* rowst = nc + 64;                      // 64
        int* red   = rowst + 64;                   // 512
        if (t < 64) nc[t] = 0;
        int s = 0;                                 // bucket base: sum of ccnt[0..b)
        for (int i = t; i < b; i += 512) s += ccnt[i];
        red[t] = s;
        __syncthreads();
        for (int off = 256; off > 0; off >>= 1) {
            if (t < off) red[t] += red[t + off];
            __syncthreads();
        }
        const int cnt = min(ccnt[b], BCAP);
        const unsigned* p = cbuf + (size_t)b * BCAP;
        unsigned w2[4];
        int rank[4];
        #pragma unroll
        for (int k = 0; k < 4; ++k) {
            int e = t + k * 512;
            if (e < cnt) {
                w2[k] = p[e];
                rank[k] = atomicAdd(&nc[(w2[k] >> 16) & 63], 1);
            }
        }
        __syncthreads();
        if (t < 64) {                              // wave 0: scan 64 node counts
            int v = nc[t];
            counts[b * 64 + t] = v;
            int inc = v;
            #pragma unroll
            for (int off = 1; off < 64; off <<= 1) {
                int n = __shfl_up(inc, off, 64);
                if (t >= off) inc += n;
            }
            int rs = red[0] + inc - v;             // exclusive + bucket base
            row_start[b * 64 + t] = rs;
            rowst[t] = rs;
        }
        __syncthreads();
        #pragma unroll
        for (int k = 0; k < 4; ++k) {
            int e = t + k * 512;
            if (e < cnt) {
                int d = (w2[k] >> 16) & 63;
                csr[rowst[d] + rank[k]] = (int)(w2[k] & 0xffffu);
            }
        }
    }
}

// ---------------------------------------------------------------- aggregation
// one wave per dst node; 64 lanes per edge. Lane owns channels [4l,4l+4); head = l>>4.
// Lean math (factorized lrelu dot, fixed-max exp2 softmax), vectorized index fetch,
// 4 gathers in flight, dual A/B chains. att scaled by 0.6*log2e at load.
// At the LLC->L2 random-fill floor: 272MB @ ~3.3 TB/s ~= 83us (R6-R14 invariant;
// depth-8 prefetch and deeper pipelines do NOT move it -- fill-bandwidth-bound).
__global__ __launch_bounds__(256) void k_aggregate(const unsigned short* __restrict__ xs_bf,
                                                   const unsigned short* __restrict__ xd_bf,
                                                   const int* __restrict__ row_start,
                                                   const int* __restrict__ counts,
                                                   const int* __restrict__ csr,
                                                   const float* __restrict__ att,
                                                   const float* __restrict__ bias,
                                                   float* __restrict__ out) {
    const int t = threadIdx.x;
    const int lane = t & 63;
    const int node  = __builtin_amdgcn_readfirstlane(blockIdx.x * 4 + (t >> 6));
    const int start = __builtin_amdgcn_readfirstlane(row_start[node]);
    const int deg   = __builtin_amdgcn_readfirstlane(counts[node]);
    const int total = deg + 1;                     // item 0 = self loop, i>=1 -> csr[i-1]

    // per-lane constants: att*0.6*log2e and xd for 4 channels
    const float CATT = 0.6f * 1.44269504088896f;
    f32x2 att01, att23, xd01, xd23;
    {
        float4 a = *(const float4*)(att + lane * 4);
        att01.x = CATT * a.x; att01.y = CATT * a.y;
        att23.x = CATT * a.z; att23.y = CATT * a.w;
        uint2 xw = *(const uint2*)(xd_bf + (size_t)node * NHID + lane * 4);
        xd01.x = bflo(xw.x); xd01.y = bfhi(xw.x);
        xd23.x = bflo(xw.y); xd23.y = bfhi(xw.y);
    }

    const char* xsb = (const char*)xs_bf;
    const unsigned voff = (unsigned)lane * 8;
    float ssumA = 0.f, ssumB = 0.f;
    f32x2 accA01 = {0.f, 0.f}, accA23 = {0.f, 0.f};
    f32x2 accB01 = {0.f, 0.f}, accB23 = {0.f, 0.f};

#define LDX(S) (*(const uint2*)(xsb + (((size_t)(unsigned)(S)) << 9) + voff))
#define PROC(U, GUARD, KOFF, SS, A01, A23) {                                   \
        f32x2 c01, c23;                                                        \
        c01.x = bflo((U).x); c01.y = bfhi((U).x);                              \
        c23.x = bflo((U).y); c23.y = bfhi((U).y);                              \
        f32x2 sv01 = c01 + xd01, sv23 = c23 + xd23;                            \
        f32x2 dA2 = att01 * c01 + att23 * c23;                                 \
        f32x2 a01v, a23v;                                                      \
        a01v.x = fabsf(sv01.x); a01v.y = fabsf(sv01.y);                        \
        a23v.x = fabsf(sv23.x); a23v.y = fabsf(sv23.y);                        \
        f32x2 dB2 = att01 * a01v + att23 * a23v;                               \
        float d_ = fmaf(0.66666667f, dB2.x + dB2.y, dA2.x + dA2.y);            \
        d_ = dpp_add<0xB1>(d_);                                                \
        d_ = dpp_add<0x4E>(d_);                                                \
        d_ = dpp_add<0x141>(d_);                                               \
        d_ = dpp_add<0x140>(d_);                /* 16-lane head sum */         \
        if (GUARD && j + (KOFF) >= cnt) d_ = -1e30f;                           \
        float p_ = __builtin_amdgcn_exp2f(d_);                                 \
        SS += p_;                                                              \
        f32x2 p2 = {p_, p_};                                                   \
        A01 += p2 * c01; A23 += p2 * c23; }

    for (int base = 0; base < total; base += 64) {
        const int cnt = __builtin_amdgcn_readfirstlane(min(64, total - base));
        // coalesced index load: lane holds item (base+lane); pads/self -> node
        int item = base + lane;
        int idx = node;
        if ((unsigned)(item - 1) < (unsigned)deg)
            idx = csr[start + item - 1];
        // prologue: 4 loads in flight
        uint2 c0 = LDX(__builtin_amdgcn_readlane(idx, 0));
        uint2 c1 = LDX(__builtin_amdgcn_readlane(idx, 1));
        uint2 c2 = LDX(__builtin_amdgcn_readlane(idx, 2));
        uint2 c3 = LDX(__builtin_amdgcn_readlane(idx, 3));
        int j = 0;
        for (; j + 4 <= cnt; j += 4) {         // full quads: no pad compares
            uint2 u0 = c0, u1 = c1, u2 = c2, u3 = c3;
            if (j + 4 < cnt) {
                c0 = LDX(__builtin_amdgcn_readlane(idx, j + 4));
                c1 = LDX(__builtin_amdgcn_readlane(idx, j + 5));
                c2 = LDX(__builtin_amdgcn_readlane(idx, j + 6));
                c3 = LDX(__builtin_amdgcn_readlane(idx, j + 7));
            }
            PROC(u0, false, 0, ssumA, accA01, accA23)
            PROC(u1, false, 1, ssumB, accB01, accB23)
            PROC(u2, false, 2, ssumA, accA01, accA23)
            PROC(u3, false, 3, ssumB, accB01, accB23)
        }
        if (j < cnt) {                         // tail: 1-3 items, compare-guarded
            uint2 u0 = c0, u1 = c1, u2 = c2, u3 = c3;
            PROC(u0, true, 0, ssumA, accA01, accA23)
            PROC(u1, true, 1, ssumB, accB01, accB23)
            PROC(u2, true, 2, ssumA, accA01, accA23)
            PROC(u3, true, 3, ssumB, accB01, accB23)
        }
    }
#undef PROC
#undef LDX

    // exact merge (fixed-max softmax: plain add)
    float ssum = ssumA + ssumB;
    f32x2 acc01 = accA01 + accB01;
    f32x2 acc23 = accA23 + accB23;

    float inv = __builtin_amdgcn_rcpf(ssum);
    float r0 = acc01.x * inv, r1 = acc01.y * inv;
    float r2 = acc23.x * inv, r3 = acc23.y * inv;
    // head mean: heads of this hid block live at lanes l, l^16, l^32, l^48
    r0 += __shfl_xor(r0, 16, 64); r0 += __shfl_xor(r0, 32, 64);
    r1 += __shfl_xor(r1, 16, 64); r1 += __shfl_xor(r1, 32, 64);
    r2 += __shfl_xor(r2, 16, 64); r2 += __shfl_xor(r2, 32, 64);
    r3 += __shfl_xor(r3, 16, 64); r3 += __shfl_xor(r3, 32, 64);
    if (lane < 16) {
        float4 b4 = *(const float4*)(bias + lane * 4);
        float o0 = r0 * 0.25f + b4.x;
        float o1 = r1 * 0.25f + b4.y;
        float o2 = r2 * 0.25f + b4.z;
        float o3 = r3 * 0.25f + b4.w;
        o0 = (o0 > 0.f) ? o0 : __builtin_amdgcn_exp2f(o0 * 1.44269504f) - 1.0f;
        o1 = (o1 > 0.f) ? o1 : __builtin_amdgcn_exp2f(o1 * 1.44269504f) - 1.0f;
        o2 = (o2 > 0.f) ? o2 : __builtin_amdgcn_exp2f(o2 * 1.44269504f) - 1.0f;
        o3 = (o3 > 0.f) ? o3 : __builtin_amdgcn_exp2f(o3 * 1.44269504f) - 1.0f;
        float4 o = {o0, o1, o2, o3};
        *(float4*)(out + (size_t)node * HID + lane * 4) = o;
    }
}

// ---------------------------------------------------------------- launch
extern "C" void kernel_launch(void* const* d_in, const int* in_sizes, int n_in,
                              void* d_out, int out_size, void* d_ws, size_t ws_size,
                              hipStream_t stream) {
    const float* x     = (const float*)d_in[0];
    const int*   ei    = (const int*)d_in[1];
    const float* gamma = (const float*)d_in[4];
    const float* beta  = (const float*)d_in[5];
    const float* w_l   = (const float*)d_in[6];
    const float* b_l   = (const float*)d_in[7];
    const float* w_r   = (const float*)d_in[8];
    const float* b_r   = (const float*)d_in[9];
    const float* att   = (const float*)d_in[10];
    const float* bias  = (const float*)d_in[11];
    float* out = (float*)d_out;

    char* ws = (char*)d_ws;
    unsigned short* xs_bf = (unsigned short*)ws;                        // 32 MB
    unsigned short* xd_bf = xs_bf + (size_t)N_NODES * NHID;             // 32 MB
    unsigned short* xhi   = xd_bf + (size_t)N_NODES * NHID;             // 16 MB
    unsigned short* Whi   = xhi + (size_t)N_NODES * F_IN;               // 128 KB
    float* bp      = (float*)(Whi + 512 * F_IN);                        // 512
    float* sums    = bp + 512;                                          // 256  (memset from here)
    int* ccnt      = (int*)(sums + 256);                                // 1024 (memset to here)
    int* counts    = ccnt + NBUCK;                                      // 65536
    int* row_start = counts + N_NODES;                                  // 65536
    int* csr       = row_start + N_NODES;                               // 1048576
    unsigned* cbuf = (unsigned*)(csr + N_EDGES);                        // 8 MB

    (void)hipMemsetAsync(sums, 0, (256 + NBUCK) * sizeof(float), stream);

    k_front<<<512, 256, 0, stream>>>(x, sums, xhi, ei, ccnt, cbuf);
    k_prep_w<<<128, 256, 0, stream>>>(w_l, b_l, w_r, b_r, gamma, beta, sums, Whi, bp);
    k_gemm_fine<<<3072, 512, 0, stream>>>(xhi, Whi, bp, xs_bf, xd_bf,
                                          cbuf, ccnt, counts, row_start, csr);
    k_aggregate<<<N_NODES / 4, 256, 0, stream>>>(xs_bf, xd_bf, row_start, counts, csr,
                                                 att, bias, out);
}